// Round 3
// baseline (1296.591 us; speedup 1.0000x reference)
//
#include <hip/hip_runtime.h>
#include <math.h>

// Problem constants
#define NTOK   49       // tokens per window (7*7)
#define DIM    192
#define HEADS  6
#define HD     32
#define NWIN   64       // distinct masks
#define BWIN   4096     // number of windows
#define K3     576      // 3*DIM
#define MROWS  (BWIN * NTOK)   // 200704

// ---------------------------------------------------------------------------
// GEMM: C[M,N] = A[M,192] * W[N,192]^T + bias[N]
// A row stride = lda (192 for x, 576 when reading the q-third of qkv).
// 64x64 tile, BK=32, 256 threads, 4x4 accum per thread.
// LDS k-major, stride 68 (272B = 17*16B -> float4 reads stay 16B-aligned,
// bank aliasing <=2-way which is free on CDNA4).
// ---------------------------------------------------------------------------
__global__ __launch_bounds__(256) void gemm_xwT(
    const float* __restrict__ A, const float* __restrict__ W,
    const float* __restrict__ bias, float* __restrict__ C, int N, int lda)
{
    __shared__ float As[32][68];
    __shared__ float Ws[32][68];

    const int m0 = blockIdx.x * 64;
    const int n0 = blockIdx.y * 64;
    const int t  = threadIdx.x;
    const int tx = t & 15;   // n-dim (16 threads * 4 cols)
    const int ty = t >> 4;   // m-dim (16 threads * 4 rows)

    // loader mapping: 64 rows x 8 float4-cols = 512 float4s, 2 per thread
    const int lrow = t >> 3;  // 0..31
    const int lc4  = t & 7;   // 0..7

    // init accum with bias (same across rows)
    const float4 bb = *(const float4*)(bias + n0 + tx * 4);
    float4 acc0 = bb, acc1 = bb, acc2 = bb, acc3 = bb;

    const float* Aptr = A + (size_t)m0 * lda;
    const float* Wptr = W + (size_t)n0 * 192;

    for (int kt = 0; kt < 192; kt += 32) {
        const float4 a0 = *(const float4*)(Aptr + (size_t)(lrow)      * lda + kt + lc4 * 4);
        const float4 a1 = *(const float4*)(Aptr + (size_t)(lrow + 32) * lda + kt + lc4 * 4);
        const float4 w0 = *(const float4*)(Wptr + (size_t)(lrow)      * 192 + kt + lc4 * 4);
        const float4 w1 = *(const float4*)(Wptr + (size_t)(lrow + 32) * 192 + kt + lc4 * 4);

        __syncthreads();   // previous compute must finish before LDS overwrite

        As[lc4*4+0][lrow]    = a0.x; As[lc4*4+1][lrow]    = a0.y;
        As[lc4*4+2][lrow]    = a0.z; As[lc4*4+3][lrow]    = a0.w;
        As[lc4*4+0][lrow+32] = a1.x; As[lc4*4+1][lrow+32] = a1.y;
        As[lc4*4+2][lrow+32] = a1.z; As[lc4*4+3][lrow+32] = a1.w;
        Ws[lc4*4+0][lrow]    = w0.x; Ws[lc4*4+1][lrow]    = w0.y;
        Ws[lc4*4+2][lrow]    = w0.z; Ws[lc4*4+3][lrow]    = w0.w;
        Ws[lc4*4+0][lrow+32] = w1.x; Ws[lc4*4+1][lrow+32] = w1.y;
        Ws[lc4*4+2][lrow+32] = w1.z; Ws[lc4*4+3][lrow+32] = w1.w;

        __syncthreads();

        #pragma unroll
        for (int k = 0; k < 32; ++k) {
            const float4 af = *(const float4*)&As[k][ty * 4];  // 4 m-rows
            const float4 wf = *(const float4*)&Ws[k][tx * 4];  // 4 n-cols
            acc0.x = fmaf(af.x, wf.x, acc0.x); acc0.y = fmaf(af.x, wf.y, acc0.y);
            acc0.z = fmaf(af.x, wf.z, acc0.z); acc0.w = fmaf(af.x, wf.w, acc0.w);
            acc1.x = fmaf(af.y, wf.x, acc1.x); acc1.y = fmaf(af.y, wf.y, acc1.y);
            acc1.z = fmaf(af.y, wf.z, acc1.z); acc1.w = fmaf(af.y, wf.w, acc1.w);
            acc2.x = fmaf(af.z, wf.x, acc2.x); acc2.y = fmaf(af.z, wf.y, acc2.y);
            acc2.z = fmaf(af.z, wf.z, acc2.z); acc2.w = fmaf(af.z, wf.w, acc2.w);
            acc3.x = fmaf(af.w, wf.x, acc3.x); acc3.y = fmaf(af.w, wf.y, acc3.y);
            acc3.z = fmaf(af.w, wf.z, acc3.z); acc3.w = fmaf(af.w, wf.w, acc3.w);
        }
    }

    float* Cp = C + (size_t)(m0 + ty * 4) * N + n0 + tx * 4;
    *(float4*)(Cp + 0 * (size_t)N) = acc0;
    *(float4*)(Cp + 1 * (size_t)N) = acc1;
    *(float4*)(Cp + 2 * (size_t)N) = acc2;
    *(float4*)(Cp + 3 * (size_t)N) = acc3;
}

// ---------------------------------------------------------------------------
// Precompute fused[wb][h][j][i] = mask[wb][i][j] + bias_table[rel_index[i][j]][h]
// Layout chosen so the attention kernel's per-j read over lanes (i) is coalesced.
// ---------------------------------------------------------------------------
#define FUSED_TOTAL (NWIN * HEADS * NTOK * NTOK)   // 921984

__global__ __launch_bounds__(256) void fuse_mask_bias(
    const float* __restrict__ mask, const float* __restrict__ bt,
    const int* __restrict__ rel, float* __restrict__ fused)
{
    int idx = blockIdx.x * 256 + threadIdx.x;
    if (idx >= FUSED_TOTAL) return;
    int i  = idx % NTOK;
    int j  = (idx / NTOK) % NTOK;
    int h  = (idx / (NTOK * NTOK)) % HEADS;
    int wb = idx / (NTOK * NTOK * HEADS);
    fused[idx] = mask[((size_t)wb * NTOK + i) * NTOK + j]
               + bt[rel[i * NTOK + j] * HEADS + h];
}

// ---------------------------------------------------------------------------
// Attention: one wave per (window b, head h). Lane i owns q/output row i.
// q row kept in registers; k[j]/v[j] are broadcast loads (same addr all lanes;
// each window's 112KB qkv block is L2-hot, read once per (b,h) -> no LDS stage).
// Output is written IN-PLACE into the q columns of qkv (lane reads its own q
// first, writes its own row last; other heads touch disjoint columns), saving
// a separate 154MB attnout buffer. NOTE: qkv deliberately NOT __restrict__.
// ---------------------------------------------------------------------------
__global__ __launch_bounds__(64) void attn_win(
    float* qkv, const float* __restrict__ fused)
{
    const int b    = blockIdx.x;
    const int h    = blockIdx.y;
    const int lane = threadIdx.x;
    const int wb   = b & (NWIN - 1);

    __shared__ float S[NTOK * 50];   // lane-private rows, stride 50

    float* base = qkv + (size_t)b * NTOK * K3;
    const float scale = 0.17677669529663687f;  // 1/sqrt(32)
    const bool active = lane < NTOK;

    float4 q[8];
    if (active) {
        const float* qp = base + (size_t)lane * K3 + h * HD;
        #pragma unroll
        for (int c = 0; c < 8; ++c) {
            q[c] = *(const float4*)(qp + 4 * c);
            q[c].x *= scale; q[c].y *= scale; q[c].z *= scale; q[c].w *= scale;
        }
    }

    float m = -1e30f;
    const float* fb = fused + ((size_t)(wb * HEADS + h) * NTOK) * NTOK; // [j][i]

    if (active) {
        #pragma unroll 7
        for (int j = 0; j < NTOK; ++j) {
            const float* kp = base + (size_t)j * K3 + DIM + h * HD;
            float4 s4 = {0.f, 0.f, 0.f, 0.f};
            #pragma unroll
            for (int c = 0; c < 8; ++c) {
                const float4 kf = *(const float4*)(kp + 4 * c);
                s4.x = fmaf(q[c].x, kf.x, s4.x);
                s4.y = fmaf(q[c].y, kf.y, s4.y);
                s4.z = fmaf(q[c].z, kf.z, s4.z);
                s4.w = fmaf(q[c].w, kf.w, s4.w);
            }
            float s = (s4.x + s4.y) + (s4.z + s4.w);
            s += fb[j * NTOK + lane];           // coalesced over lanes
            S[lane * 50 + j] = s;
            m = fmaxf(m, s);
        }

        float l = 0.f;
        float4 o[8];
        #pragma unroll
        for (int c = 0; c < 8; ++c) o[c] = make_float4(0.f, 0.f, 0.f, 0.f);

        #pragma unroll 7
        for (int j = 0; j < NTOK; ++j) {
            const float p = __expf(S[lane * 50 + j] - m);
            l += p;
            const float* vp = base + (size_t)j * K3 + 2 * DIM + h * HD;
            #pragma unroll
            for (int c = 0; c < 8; ++c) {
                const float4 vf = *(const float4*)(vp + 4 * c);
                o[c].x = fmaf(p, vf.x, o[c].x);
                o[c].y = fmaf(p, vf.y, o[c].y);
                o[c].z = fmaf(p, vf.z, o[c].z);
                o[c].w = fmaf(p, vf.w, o[c].w);
            }
        }

        const float rl = 1.0f / l;
        // write in-place into this row's q columns [h*32, h*32+32)
        float* op = base + (size_t)lane * K3 + h * HD;
        #pragma unroll
        for (int c = 0; c < 8; ++c) {
            float4 r = o[c];
            r.x *= rl; r.y *= rl; r.z *= rl; r.w *= rl;
            *(float4*)(op + 4 * c) = r;
        }
    }
}

// ---------------------------------------------------------------------------
// Launch. ws layout: qkv (462.4 MB) | fused (3.7 MB)  -- attn output reuses
// the q-third of qkv (proj GEMM reads it with lda=576).
// ---------------------------------------------------------------------------
extern "C" void kernel_launch(void* const* d_in, const int* in_sizes, int n_in,
                              void* d_out, int out_size, void* d_ws, size_t ws_size,
                              hipStream_t stream)
{
    const float* x      = (const float*)d_in[0];
    const float* mask   = (const float*)d_in[1];
    const float* qkv_w  = (const float*)d_in[2];
    const float* qkv_b  = (const float*)d_in[3];
    const float* proj_w = (const float*)d_in[4];
    const float* proj_b = (const float*)d_in[5];
    const float* bt     = (const float*)d_in[6];
    const int*   rel    = (const int*)d_in[7];
    float* out = (float*)d_out;

    char* ws = (char*)d_ws;
    float* qkv   = (float*)ws;
    float* fused = (float*)(ws + (size_t)MROWS * K3 * 4);

    // 1) QKV GEMM: [200704,192] x [576,192]^T -> [200704,576]
    gemm_xwT<<<dim3(MROWS / 64, K3 / 64), dim3(256), 0, stream>>>(
        x, qkv_w, qkv_b, qkv, K3, DIM);

    // 2) fused mask+bias table
    fuse_mask_bias<<<dim3((FUSED_TOTAL + 255) / 256), dim3(256), 0, stream>>>(
        mask, bt, rel, fused);

    // 3) attention per (window, head); output lands in q-third of qkv
    attn_win<<<dim3(BWIN, HEADS), dim3(64), 0, stream>>>(qkv, fused);

    // 4) proj GEMM: [200704,192](stride 576) x [192,192]^T -> [200704,192]
    gemm_xwT<<<dim3(MROWS / 64, DIM / 64), dim3(256), 0, stream>>>(
        qkv, proj_w, proj_b, out, DIM, K3);
}

// Round 4
// 858.093 us; speedup vs baseline: 1.5110x; 1.5110x over previous
//
#include <hip/hip_runtime.h>
#include <math.h>

// Problem constants
#define NTOK   49
#define DIM    192
#define HEADS  6
#define HD     32
#define NWIN   64
#define BWIN   4096
#define K3     576
#define MROWS  (BWIN * NTOK)   // 200704

typedef __attribute__((ext_vector_type(8))) short  short8v;
typedef __attribute__((ext_vector_type(4))) float  float4v;

__device__ __forceinline__ unsigned short f2bf(float f) {
    union { float f; unsigned u; } v; v.f = f;
    unsigned r = v.u + 0x7FFFu + ((v.u >> 16) & 1u);   // RNE
    return (unsigned short)(r >> 16);
}

// ---------------------------------------------------------------------------
// fp32 -> bf16 converter (for weights)
// ---------------------------------------------------------------------------
__global__ __launch_bounds__(256) void cvt_bf16(
    const float* __restrict__ src, unsigned short* __restrict__ dst, int n)
{
    int i = blockIdx.x * 256 + threadIdx.x;
    if (i < n) dst[i] = f2bf(src[i]);
}

// ---------------------------------------------------------------------------
// MFMA GEMM: C[M,N] = A[M,192](fp32, row stride lda) * Wb[N,192](bf16)^T + bias
// BM=128, BN=96, BK=64. 256 thr = 4 waves (2Mx2N), wave tile 64x48 = acc[4][3]
// of 16x16x32 bf16 MFMA fragments.
// LDS: As[128][64], Bs[96][64] bf16, row stride 128B, 16B-slot XOR swizzle
// (slot ^= row&7) on write AND read -> conflict-free fragment ds_read_b128.
// Frag layout (m89/m91-verified): a from A rows, b from W rows;
// D lane l reg j -> C[row = fq*4+j][col = fr], fq=l>>4, fr=l&15.
// ---------------------------------------------------------------------------
__global__ __launch_bounds__(256) void gemm_mfma(
    const float* __restrict__ A, const unsigned short* __restrict__ Wb,
    const float* __restrict__ bias, float* __restrict__ C, int N, int lda)
{
    __shared__ unsigned short As[128 * 64];
    __shared__ unsigned short Bs[96 * 64];

    const int t    = threadIdx.x;
    const int wid  = t >> 6;
    const int lane = t & 63;
    const int wr   = wid >> 1;          // wave m: 0/1
    const int wc   = wid & 1;           // wave n: 0/1
    const int fr   = lane & 15;
    const int fq   = lane >> 4;

    const int m0 = blockIdx.x * 128;
    const int n0 = blockIdx.y * 96;

    // accumulators, bias-initialized (bias depends only on col = fr-indexed)
    float4v acc[4][3];
    #pragma unroll
    for (int nf = 0; nf < 3; ++nf) {
        const float bv = bias[n0 + wc * 48 + nf * 16 + fr];
        #pragma unroll
        for (int mf = 0; mf < 4; ++mf)
            acc[mf][nf] = (float4v){bv, bv, bv, bv};
    }

    // A staging map: thread -> (row ar, 32-elem half ah)
    const int ar = t >> 1;
    const int ah = t & 1;

    for (int kt = 0; kt < 192; kt += 64) {
        __syncthreads();   // prior MFMA reads done before LDS overwrite

        // ---- stage A: fp32 load, cvt, swizzled ds_write (32 elems/thread)
        {
            const float* ap = A + (size_t)(m0 + ar) * lda + kt + ah * 32;
            unsigned short tmp[32];
            #pragma unroll
            for (int u = 0; u < 8; ++u) {
                const float4 f = *(const float4*)(ap + u * 4);
                tmp[u * 4 + 0] = f2bf(f.x); tmp[u * 4 + 1] = f2bf(f.y);
                tmp[u * 4 + 2] = f2bf(f.z); tmp[u * 4 + 3] = f2bf(f.w);
            }
            #pragma unroll
            for (int s2 = 0; s2 < 4; ++s2) {
                const int slot = ah * 4 + s2;
                const int phys = slot ^ (ar & 7);
                *(short8v*)&As[ar * 64 + phys * 8] = *(short8v*)&tmp[s2 * 8];
            }
        }
        // ---- stage B: bf16 load, swizzled ds_write (768 16B-chunks total)
        #pragma unroll
        for (int i = 0; i < 3; ++i) {
            const int c   = i * 256 + t;
            const int row = c >> 3;
            const int sl  = c & 7;
            const short8v bv8 = *(const short8v*)(Wb + (size_t)(n0 + row) * 192 + kt + sl * 8);
            *(short8v*)&Bs[row * 64 + (sl ^ (row & 7)) * 8] = bv8;
        }

        __syncthreads();

        // ---- MFMA: 2 x K=32 sub-steps, 12 MFMA each
        #pragma unroll
        for (int ks = 0; ks < 2; ++ks) {
            short8v af[4], bf[3];
            #pragma unroll
            for (int mf = 0; mf < 4; ++mf) {
                const int row = wr * 64 + mf * 16 + fr;
                af[mf] = *(const short8v*)&As[row * 64 + ((ks * 4 + fq) ^ (row & 7)) * 8];
            }
            #pragma unroll
            for (int nf = 0; nf < 3; ++nf) {
                const int row = wc * 48 + nf * 16 + fr;
                bf[nf] = *(const short8v*)&Bs[row * 64 + ((ks * 4 + fq) ^ (row & 7)) * 8];
            }
            #pragma unroll
            for (int mf = 0; mf < 4; ++mf)
                #pragma unroll
                for (int nf = 0; nf < 3; ++nf)
                    acc[mf][nf] = __builtin_amdgcn_mfma_f32_16x16x32_bf16(
                        af[mf], bf[nf], acc[mf][nf], 0, 0, 0);
        }
    }

    // ---- epilogue: fp32 store
    #pragma unroll
    for (int mf = 0; mf < 4; ++mf) {
        #pragma unroll
        for (int nf = 0; nf < 3; ++nf) {
            const int col = n0 + wc * 48 + nf * 16 + fr;
            #pragma unroll
            for (int j = 0; j < 4; ++j) {
                const int row = m0 + wr * 64 + mf * 16 + fq * 4 + j;
                C[(size_t)row * N + col] = acc[mf][nf][j];
            }
        }
    }
}

// ---------------------------------------------------------------------------
// fused[wb][h][j][i] = mask[wb][i][j] + bias_table[rel_index[i][j]][h]
// ---------------------------------------------------------------------------
#define FUSED_TOTAL (NWIN * HEADS * NTOK * NTOK)

__global__ __launch_bounds__(256) void fuse_mask_bias(
    const float* __restrict__ mask, const float* __restrict__ bt,
    const int* __restrict__ rel, float* __restrict__ fused)
{
    int idx = blockIdx.x * 256 + threadIdx.x;
    if (idx >= FUSED_TOTAL) return;
    int i  = idx % NTOK;
    int j  = (idx / NTOK) % NTOK;
    int h  = (idx / (NTOK * NTOK)) % HEADS;
    int wb = idx / (NTOK * NTOK * HEADS);
    fused[idx] = mask[((size_t)wb * NTOK + i) * NTOK + j]
               + bt[rel[i * NTOK + j] * HEADS + h];
}

// ---------------------------------------------------------------------------
// Attention (UNCHANGED from round 3, proven): one wave per (window, head).
// ---------------------------------------------------------------------------
__global__ __launch_bounds__(64) void attn_win(
    float* qkv, const float* __restrict__ fused)
{
    const int b    = blockIdx.x;
    const int h    = blockIdx.y;
    const int lane = threadIdx.x;
    const int wb   = b & (NWIN - 1);

    __shared__ float S[NTOK * 50];

    float* base = qkv + (size_t)b * NTOK * K3;
    const float scale = 0.17677669529663687f;
    const bool active = lane < NTOK;

    float4 q[8];
    if (active) {
        const float* qp = base + (size_t)lane * K3 + h * HD;
        #pragma unroll
        for (int c = 0; c < 8; ++c) {
            q[c] = *(const float4*)(qp + 4 * c);
            q[c].x *= scale; q[c].y *= scale; q[c].z *= scale; q[c].w *= scale;
        }
    }

    float m = -1e30f;
    const float* fb = fused + ((size_t)(wb * HEADS + h) * NTOK) * NTOK;

    if (active) {
        #pragma unroll 7
        for (int j = 0; j < NTOK; ++j) {
            const float* kp = base + (size_t)j * K3 + DIM + h * HD;
            float4 s4 = {0.f, 0.f, 0.f, 0.f};
            #pragma unroll
            for (int c = 0; c < 8; ++c) {
                const float4 kf = *(const float4*)(kp + 4 * c);
                s4.x = fmaf(q[c].x, kf.x, s4.x);
                s4.y = fmaf(q[c].y, kf.y, s4.y);
                s4.z = fmaf(q[c].z, kf.z, s4.z);
                s4.w = fmaf(q[c].w, kf.w, s4.w);
            }
            float s = (s4.x + s4.y) + (s4.z + s4.w);
            s += fb[j * NTOK + lane];
            S[lane * 50 + j] = s;
            m = fmaxf(m, s);
        }

        float l = 0.f;
        float4 o[8];
        #pragma unroll
        for (int c = 0; c < 8; ++c) o[c] = make_float4(0.f, 0.f, 0.f, 0.f);

        #pragma unroll 7
        for (int j = 0; j < NTOK; ++j) {
            const float p = __expf(S[lane * 50 + j] - m);
            l += p;
            const float* vp = base + (size_t)j * K3 + 2 * DIM + h * HD;
            #pragma unroll
            for (int c = 0; c < 8; ++c) {
                const float4 vf = *(const float4*)(vp + 4 * c);
                o[c].x = fmaf(p, vf.x, o[c].x);
                o[c].y = fmaf(p, vf.y, o[c].y);
                o[c].z = fmaf(p, vf.z, o[c].z);
                o[c].w = fmaf(p, vf.w, o[c].w);
            }
        }

        const float rl = 1.0f / l;
        float* op = base + (size_t)lane * K3 + h * HD;
        #pragma unroll
        for (int c = 0; c < 8; ++c) {
            float4 r = o[c];
            r.x *= rl; r.y *= rl; r.z *= rl; r.w *= rl;
            *(float4*)(op + 4 * c) = r;
        }
    }
}

// ---------------------------------------------------------------------------
// Launch. ws: qkv f32 (462.4MB) | fused (3.7MB) | wb_qkv bf16 | wb_proj bf16
// ---------------------------------------------------------------------------
extern "C" void kernel_launch(void* const* d_in, const int* in_sizes, int n_in,
                              void* d_out, int out_size, void* d_ws, size_t ws_size,
                              hipStream_t stream)
{
    const float* x      = (const float*)d_in[0];
    const float* mask   = (const float*)d_in[1];
    const float* qkv_w  = (const float*)d_in[2];
    const float* qkv_b  = (const float*)d_in[3];
    const float* proj_w = (const float*)d_in[4];
    const float* proj_b = (const float*)d_in[5];
    const float* bt     = (const float*)d_in[6];
    const int*   rel    = (const int*)d_in[7];
    float* out = (float*)d_out;

    char* ws = (char*)d_ws;
    const size_t qkvB   = (size_t)MROWS * K3 * 4;          // 462,422,016
    const size_t fusedB = (size_t)FUSED_TOTAL * 4;         // 3,687,936
    float*          qkv     = (float*)ws;
    float*          fused   = (float*)(ws + qkvB);
    unsigned short* wb_qkv  = (unsigned short*)(ws + qkvB + fusedB);
    unsigned short* wb_proj = wb_qkv + (size_t)K3 * DIM;   // +221,184B

    // 0) weights -> bf16
    cvt_bf16<<<dim3((K3 * DIM + 255) / 256), dim3(256), 0, stream>>>(
        qkv_w, wb_qkv, K3 * DIM);
    cvt_bf16<<<dim3((DIM * DIM + 255) / 256), dim3(256), 0, stream>>>(
        proj_w, wb_proj, DIM * DIM);

    // 1) QKV GEMM (MFMA): [200704,192] x [576,192]^T -> fp32 [200704,576]
    gemm_mfma<<<dim3(MROWS / 128, K3 / 96), dim3(256), 0, stream>>>(
        x, wb_qkv, qkv_b, qkv, K3, DIM);

    // 2) fused mask+bias
    fuse_mask_bias<<<dim3((FUSED_TOTAL + 255) / 256), dim3(256), 0, stream>>>(
        mask, bt, rel, fused);

    // 3) attention (unchanged); output lands in q-third of qkv
    attn_win<<<dim3(BWIN, HEADS), dim3(64), 0, stream>>>(qkv, fused);

    // 4) proj GEMM (MFMA): [200704,192](lda=576) x [192,192]^T -> fp32 out
    gemm_mfma<<<dim3(MROWS / 128, DIM / 96), dim3(256), 0, stream>>>(
        qkv, wb_proj, proj_b, out, DIM, K3);
}